// Round 5
// baseline (179.691 us; speedup 1.0000x reference)
//
#include <hip/hip_runtime.h>
#include <stdint.h>

#define HWPOS 1024
#define CCH   256
#define RROWS 128   // 2B
#define EPSF  1.1920928955078125e-07f

typedef __attribute__((ext_vector_type(4))) float float4v;

__device__ __forceinline__ uint32_t pk4_fp8(float a, float b, float c, float d) {
  int v = 0;
  v = __builtin_amdgcn_cvt_pk_fp8_f32(a, b, v, false);  // bytes 0,1
  v = __builtin_amdgcn_cvt_pk_fp8_f32(c, d, v, true);   // bytes 2,3
  return (uint32_t)v;
}

// ws layout v11 (fp8 bytes), R-MAJOR: addr(r,hw,s) = r*262144 + hw*256 + s*16
//   s = swizzled 16B chunk slot: data chunk dd (c = dd*16..+15) stored at
//   slot s = dd ^ (r & 15)  -> per-256B-row image identical to v10, so the
//   gram kernel's in-LDS layout (and all verified MFMA algebra) is unchanged.
//   r-major makes transpose wave-stores land in 2KB spans (v10: 8x128B
//   fragments at 32KB stride -> channel hotspot, the suspected 1.8TB/s cap).

// ---------------------------------------------------------------------------
// Kernel 1 (v11, fp8): transpose [B,C,H,W] f32 -> ws fp8-e4m3 (layout above).
// Geometry as v10: block = 128 hw x 128 c (one c-half) x 1 r, 256 threads.
// Reads: lanes 32-wide on hw -> 2 x 512B contiguous segments per wave-load.
// Stage fp8 chunks in LDS (slot ^= hq&7), barrier, re-gather so 8 lanes emit
// one aligned 128B half-row per hw. v11 change: ONLY the global write
// addressing (r-major ws) -> per-wave stores cover 8 hw x 128B within 2KB.
// Grid: (8 hw-groups, 128 r, 2 c-halves) = 2048 blocks.
// ---------------------------------------------------------------------------
__global__ __launch_bounds__(256, 4) void k_transpose(const float* __restrict__ inp,
                                                      const float* __restrict__ tgt,
                                                      unsigned char* __restrict__ wsF,
                                                      float* __restrict__ out) {
  __shared__ uint4 Ls[1024];        // [hwl 0..127][slot 0..7], 16 KB
  const int t    = threadIdx.x;
  const int hq   = t & 31;          // hw quad (4 hw) -> 128 hw per block
  const int ddl  = t >> 5;          // local c-chunk 0..7
  const int bx   = blockIdx.x;      // hw group (128 hw each), 0..7
  const int r    = blockIdx.y;      // row 0..127
  const int half = blockIdx.z;      // c half 0..1
  if (bx == 0 && r == 0 && half == 0 && t == 0) out[0] = 0.0f;
  const int dd = half * 8 + ddl;    // global c-chunk 0..15
  const float* src = (r < 64) ? (inp + (size_t)r * CCH * HWPOS)
                              : (tgt + (size_t)(r - 64) * CCH * HWPOS);
  const float* p = src + (size_t)(dd * 16) * HWPOS + bx * 128 + hq * 4;
  float4 v[16];
#pragma unroll
  for (int e = 0; e < 16; ++e) v[e] = *(const float4*)(p + (size_t)e * HWPOS);
  // convert + stage to LDS (slot swizzled by hq&7 to spread banks)
  const int sbase = ddl ^ (hq & 7);
#pragma unroll
  for (int q = 0; q < 4; ++q) {
    float x[16];
#pragma unroll
    for (int e = 0; e < 16; ++e)
      x[e] = (q == 0) ? v[e].x : (q == 1) ? v[e].y : (q == 2) ? v[e].z : v[e].w;
    uint4 o;
    o.x = pk4_fp8(x[0],  x[1],  x[2],  x[3]);
    o.y = pk4_fp8(x[4],  x[5],  x[6],  x[7]);
    o.z = pk4_fp8(x[8],  x[9],  x[10], x[11]);
    o.w = pk4_fp8(x[12], x[13], x[14], x[15]);
    Ls[(hq * 4 + q) * 8 + sbase] = o;
  }
  __syncthreads();
  // write phase: 8 lanes (sl) emit one aligned 128B half-row per hw
  const int sl = t & 7;             // output slot within half-row
  const int hb = t >> 3;            // hw base 0..31
  const int mh = r & 7;
  const int half_out = half ^ ((r >> 3) & 1);
  const int ddn = sl ^ mh;          // local chunk that lands at slot sl
  // r-major ws: addr = r*262144 + (bx*128+hwl)*256 + half_out*128 + sl*16
  const size_t gbase = (size_t)r * 262144 + (size_t)(bx * 128) * 256
                     + (size_t)(half_out * 128 + sl * 16);
#pragma unroll
  for (int j = 0; j < 4; ++j) {
    const int hwl = hb + 32 * j;
    uint4 d = Ls[hwl * 8 + (ddn ^ ((hwl >> 2) & 7))];
    *(uint4*)(wsF + gbase + (size_t)hwl * 256) = d;
  }
}

// ---------------------------------------------------------------------------
// Kernel 2 (v6, fp8): one block per hw. Whole 32KB fp8 image in ONE LDS
// buffer. v6 change vs v5: ws is r-major, so the global_load_lds source for
// chunk ch (Fs byte ch*16) is (ch>>4)*262144 + hw*256 + (ch&15)*16 -- per
// wave: 4 x 256B full-line segments at 256KB stride. LDS dest stays linear
// (wave-uniform base + lane*16). Fs contents identical to v5 -> all MFMA /
// softmax algebra untouched.
// ---------------------------------------------------------------------------
__global__ __launch_bounds__(512, 4) void k_gram(const unsigned char* __restrict__ wsF,
                                                 float* __restrict__ out) {
  __shared__ unsigned char Fs[32768];   // full fp8 image, swizzled
  __shared__ float sInv[RROWS];
  __shared__ float wred[8];
  const int t  = threadIdx.x;
  const int hw = blockIdx.x;
  const int lane = t & 63;
  const int w    = t >> 6;        // wave id 0..7 = row-tile
  const int lid  = lane & 15;
  const int quad = lane >> 4;
  float4v acc[8];
#pragma unroll
  for (int ni = 0; ni < 8; ++ni) acc[ni] = (float4v){0.f, 0.f, 0.f, 0.f};
#pragma unroll
  for (int it = 0; it < 4; ++it) {
    const int ch = it * 512 + t;                    // Fs chunk index 0..2047
    const size_t goff = (size_t)(ch >> 4) * 262144  // r page
                      + (size_t)hw * 256
                      + (size_t)(ch & 15) * 16;     // slot within row
    __builtin_amdgcn_global_load_lds(
        (const __attribute__((address_space(1))) unsigned int*)(wsF + goff),
        (__attribute__((address_space(3))) unsigned int*)(Fs + (size_t)ch * 16),
        16, 0, 0);
  }
  __syncthreads();
  const int rowA = (w << 4) | lid;
#pragma unroll
  for (int ks = 0; ks < 8; ++ks) {
    const int d    = 2 * ks + (quad >> 1);      // data chunk for this frag
    const int off  = ((d ^ lid) << 4) + (quad & 1) * 8;  // swizzled byte off
    long a = *(const long*)&Fs[rowA * 256 + off];
#pragma unroll
    for (int ni = 0; ni < 8; ++ni) {
      long b = *(const long*)&Fs[(((ni << 4) | lid)) * 256 + off];
      acc[ni] = __builtin_amdgcn_mfma_f32_16x16x32_fp8_fp8(a, b, acc[ni], 0, 0, 0);
    }
  }
  // diagonal extract (no dynamic indexing): tile w (uniform), elem lid&3
  {
    float diagv = 0.f;
#pragma unroll
    for (int ni = 0; ni < 8; ++ni) {
      if (ni == w) {
#pragma unroll
        for (int e = 0; e < 4; ++e)
          if (e == (lid & 3)) diagv = acc[ni][e];
      }
    }
    if ((lid >> 2) == quad) {
      sInv[(w << 4) | lid] = 1.0f / fmaxf(sqrtf(diagv), EPSF);
    }
  }
  __syncthreads();
  float invj[8];
#pragma unroll
  for (int ni = 0; ni < 8; ++ni) invj[ni] = sInv[(ni << 4) | lid];
  const int tj = (w + 4) & 7;     // partner col-tile (wave-uniform)
  float lacc = 0.f;
#pragma unroll
  for (int reg = 0; reg < 4; ++reg) {
    const int rloc = quad * 4 + reg;           // local row in tile
    const int rg   = (w << 4) | rloc;          // global row 0..127
    const float invi = sInv[rg];
    float v[8];
#pragma unroll
    for (int ni = 0; ni < 8; ++ni) v[ni] = 2.0f * acc[ni][reg] * invi * invj[ni];
#pragma unroll
    for (int ni = 0; ni < 8; ++ni)
      if (ni == w && lid == rloc) v[ni] = -3.0e38f;   // mask diagonal
    float mx = v[0];
#pragma unroll
    for (int ni = 1; ni < 8; ++ni) mx = fmaxf(mx, v[ni]);
#pragma unroll
    for (int sh = 1; sh < 16; sh <<= 1) mx = fmaxf(mx, __shfl_xor(mx, sh, 16));
    float sm = 0.f;
#pragma unroll
    for (int ni = 0; ni < 8; ++ni) sm += __expf(v[ni] - mx);
#pragma unroll
    for (int sh = 1; sh < 16; sh <<= 1) sm += __shfl_xor(sm, sh, 16);
    const float lse = mx + __logf(sm);
    float cand = 0.f;
#pragma unroll
    for (int ni = 0; ni < 8; ++ni)
      if (ni == tj) cand = v[ni];                // positive-pair tile (uniform)
    const float vp = __shfl(cand, rloc, 16);
    lacc += vp - lse;                            // x16 lanes per row
  }
#pragma unroll
  for (int sh = 1; sh < 64; sh <<= 1) lacc += __shfl_xor(lacc, sh, 64);
  if (lane == 0) wred[w] = lacc;
  __syncthreads();
  if (t == 0) {
    float tot = 0.f;
#pragma unroll
    for (int i = 0; i < 8; ++i) tot += wred[i];
    // tot = 16 * sum_rows(pos) for this hw; loss = -sum/(HW*2B) with x16 dup
    atomicAdd(out, -tot * (1.0f / 2097152.0f));
  }
}

extern "C" void kernel_launch(void* const* d_in, const int* in_sizes, int n_in,
                              void* d_out, int out_size, void* d_ws, size_t ws_size,
                              hipStream_t stream) {
  const float* inp = (const float*)d_in[0];
  const float* tgt = (const float*)d_in[1];
  unsigned char* wsF = (unsigned char*)d_ws;
  k_transpose<<<dim3(8, 128, 2), 256, 0, stream>>>(inp, tgt, wsF, (float*)d_out);
  k_gram<<<dim3(HWPOS), 512, 0, stream>>>(wsF, (float*)d_out);
}

// Round 6
// 175.269 us; speedup vs baseline: 1.0252x; 1.0252x over previous
//
#include <hip/hip_runtime.h>
#include <stdint.h>

#define HWPOS 1024
#define CCH   256
#define RROWS 128   // 2B
#define EPSF  1.1920928955078125e-07f

typedef __attribute__((ext_vector_type(4))) float float4v;

__device__ __forceinline__ uint32_t pk4_fp8(float a, float b, float c, float d) {
  int v = 0;
  v = __builtin_amdgcn_cvt_pk_fp8_f32(a, b, v, false);  // bytes 0,1
  v = __builtin_amdgcn_cvt_pk_fp8_f32(c, d, v, true);   // bytes 2,3
  return (uint32_t)v;
}

// ws layout (fp8 bytes), R-MAJOR: addr(r,hw,s) = r*262144 + hw*256 + s*16
//   s = swizzled 16B chunk slot: data chunk dd stored at s = dd ^ (r & 15)
//   -> per-256B-row image identical to prior versions; gram algebra unchanged.

// ---------------------------------------------------------------------------
// Kernel 1 (v12, fp8): transpose [B,C,H,W] f32 -> ws fp8-e4m3.
// v12 change: phase-1 global reads via global_load_lds (REGISTER-FREE).
// Rounds 0-5 invariant: VGPR stuck at 36-40 -> only ~4 KB loads in flight
// per wave (regalloc always re-serializes 16 float4 loads into 4 batches;
// launch_bounds and sched_barrier both failed to move it). global_load_lds
// has no VGPR dest: 16 x 1KB per wave outstanding (vmcnt-bounded), 128 KB/CU.
//   Phase 1: 16 global_load_lds -> F32s[(wv*16+e)*1024 + lane*16]
//            (per-lane global src = 2x512B segments; linear LDS dest).
//   Phase 2: 16 ds_read_b128 (stride-16B lanes, conflict-free) recover the
//            exact v11 v[e] quads; convert + swizzled fp8 stage (unchanged).
//   Phase 3: v11 write phase unchanged (r-major ws, 2KB spans per wave).
// LDS 64+16 KB -> 2 blocks/CU. Grid (8,128,2) = 2048 blocks.
// ---------------------------------------------------------------------------
__global__ __launch_bounds__(256, 2) void k_transpose(const float* __restrict__ inp,
                                                      const float* __restrict__ tgt,
                                                      unsigned char* __restrict__ wsF,
                                                      float* __restrict__ out) {
  __shared__ float F32s[16384];     // 64 KB f32 stage: slot (wv*16+e) x 1KB
  __shared__ uint4 Ls[1024];        // 16 KB fp8 stage: [hwl 0..127][slot 0..7]
  const int t    = threadIdx.x;
  const int hq   = t & 31;          // hw quad (4 hw) -> 128 hw per block
  const int ddl  = t >> 5;          // local c-chunk 0..7
  const int bx   = blockIdx.x;      // hw group (128 hw each), 0..7
  const int r    = blockIdx.y;      // row 0..127
  const int half = blockIdx.z;      // c half 0..1
  if (bx == 0 && r == 0 && half == 0 && t == 0) out[0] = 0.0f;
  const float* src = (r < 64) ? (inp + (size_t)r * CCH * HWPOS)
                              : (tgt + (size_t)(r - 64) * CCH * HWPOS);
  // phase 1: register-free staging. wave wv loads chunks {2wv, 2wv+1}.
  // desired dest byte = (wv*16+e)*1024 + (t&63)*16; pass per-lane addr
  // (k_gram convention): HW uses firstlane base + lane*16, which matches.
  const float* p = src + (size_t)(half * 128 + ddl * 16) * HWPOS + bx * 128 + hq * 4;
  const int wv = t >> 6;
#pragma unroll
  for (int e = 0; e < 16; ++e) {
    __builtin_amdgcn_global_load_lds(
        (const __attribute__((address_space(1))) unsigned int*)(p + (size_t)e * HWPOS),
        (__attribute__((address_space(3))) unsigned int*)
            ((unsigned char*)F32s + (wv * 16 + e) * 1024 + (t & 63) * 16),
        16, 0, 0);
  }
  __syncthreads();
  // phase 2: recover v[e] (float4 over 4 hw at c = half*128 + ddl*16 + e)
  float4 v[16];
#pragma unroll
  for (int e = 0; e < 16; ++e)
    v[e] = *(const float4*)((const unsigned char*)F32s
            + ((ddl >> 1) * 16 + e) * 1024 + (ddl & 1) * 512 + hq * 16);
  // convert + stage to LDS (slot swizzled by hq&7 to spread banks)
  const int sbase = ddl ^ (hq & 7);
#pragma unroll
  for (int q = 0; q < 4; ++q) {
    float x[16];
#pragma unroll
    for (int e = 0; e < 16; ++e)
      x[e] = (q == 0) ? v[e].x : (q == 1) ? v[e].y : (q == 2) ? v[e].z : v[e].w;
    uint4 o;
    o.x = pk4_fp8(x[0],  x[1],  x[2],  x[3]);
    o.y = pk4_fp8(x[4],  x[5],  x[6],  x[7]);
    o.z = pk4_fp8(x[8],  x[9],  x[10], x[11]);
    o.w = pk4_fp8(x[12], x[13], x[14], x[15]);
    Ls[(hq * 4 + q) * 8 + sbase] = o;
  }
  __syncthreads();
  // phase 3: 8 lanes (sl) emit one aligned 128B half-row per hw (r-major ws)
  const int sl = t & 7;             // output slot within half-row
  const int hb = t >> 3;            // hw base 0..31
  const int mh = r & 7;
  const int half_out = half ^ ((r >> 3) & 1);
  const int ddn = sl ^ mh;          // local chunk that lands at slot sl
  const size_t gbase = (size_t)r * 262144 + (size_t)(bx * 128) * 256
                     + (size_t)(half_out * 128 + sl * 16);
#pragma unroll
  for (int j = 0; j < 4; ++j) {
    const int hwl = hb + 32 * j;
    uint4 d = Ls[hwl * 8 + (ddn ^ ((hwl >> 2) & 7))];
    *(uint4*)(wsF + gbase + (size_t)hwl * 256) = d;
  }
}

// ---------------------------------------------------------------------------
// Kernel 2 (v6, fp8): one block per hw. Whole 32KB fp8 image in ONE LDS
// buffer. r-major ws: global_load_lds source for chunk ch is
// (ch>>4)*262144 + hw*256 + (ch&15)*16 -- per wave 4 x 256B full-line
// segments. LDS dest linear. Fs contents identical -> MFMA/softmax algebra
// (verified absmax 0) untouched.
// ---------------------------------------------------------------------------
__global__ __launch_bounds__(512, 4) void k_gram(const unsigned char* __restrict__ wsF,
                                                 float* __restrict__ out) {
  __shared__ unsigned char Fs[32768];   // full fp8 image, swizzled
  __shared__ float sInv[RROWS];
  __shared__ float wred[8];
  const int t  = threadIdx.x;
  const int hw = blockIdx.x;
  const int lane = t & 63;
  const int w    = t >> 6;        // wave id 0..7 = row-tile
  const int lid  = lane & 15;
  const int quad = lane >> 4;
  float4v acc[8];
#pragma unroll
  for (int ni = 0; ni < 8; ++ni) acc[ni] = (float4v){0.f, 0.f, 0.f, 0.f};
#pragma unroll
  for (int it = 0; it < 4; ++it) {
    const int ch = it * 512 + t;                    // Fs chunk index 0..2047
    const size_t goff = (size_t)(ch >> 4) * 262144  // r page
                      + (size_t)hw * 256
                      + (size_t)(ch & 15) * 16;     // slot within row
    __builtin_amdgcn_global_load_lds(
        (const __attribute__((address_space(1))) unsigned int*)(wsF + goff),
        (__attribute__((address_space(3))) unsigned int*)(Fs + (size_t)ch * 16),
        16, 0, 0);
  }
  __syncthreads();
  const int rowA = (w << 4) | lid;
#pragma unroll
  for (int ks = 0; ks < 8; ++ks) {
    const int d    = 2 * ks + (quad >> 1);      // data chunk for this frag
    const int off  = ((d ^ lid) << 4) + (quad & 1) * 8;  // swizzled byte off
    long a = *(const long*)&Fs[rowA * 256 + off];
#pragma unroll
    for (int ni = 0; ni < 8; ++ni) {
      long b = *(const long*)&Fs[(((ni << 4) | lid)) * 256 + off];
      acc[ni] = __builtin_amdgcn_mfma_f32_16x16x32_fp8_fp8(a, b, acc[ni], 0, 0, 0);
    }
  }
  // diagonal extract (no dynamic indexing): tile w (uniform), elem lid&3
  {
    float diagv = 0.f;
#pragma unroll
    for (int ni = 0; ni < 8; ++ni) {
      if (ni == w) {
#pragma unroll
        for (int e = 0; e < 4; ++e)
          if (e == (lid & 3)) diagv = acc[ni][e];
      }
    }
    if ((lid >> 2) == quad) {
      sInv[(w << 4) | lid] = 1.0f / fmaxf(sqrtf(diagv), EPSF);
    }
  }
  __syncthreads();
  float invj[8];
#pragma unroll
  for (int ni = 0; ni < 8; ++ni) invj[ni] = sInv[(ni << 4) | lid];
  const int tj = (w + 4) & 7;     // partner col-tile (wave-uniform)
  float lacc = 0.f;
#pragma unroll
  for (int reg = 0; reg < 4; ++reg) {
    const int rloc = quad * 4 + reg;           // local row in tile
    const int rg   = (w << 4) | rloc;          // global row 0..127
    const float invi = sInv[rg];
    float v[8];
#pragma unroll
    for (int ni = 0; ni < 8; ++ni) v[ni] = 2.0f * acc[ni][reg] * invi * invj[ni];
#pragma unroll
    for (int ni = 0; ni < 8; ++ni)
      if (ni == w && lid == rloc) v[ni] = -3.0e38f;   // mask diagonal
    float mx = v[0];
#pragma unroll
    for (int ni = 1; ni < 8; ++ni) mx = fmaxf(mx, v[ni]);
#pragma unroll
    for (int sh = 1; sh < 16; sh <<= 1) mx = fmaxf(mx, __shfl_xor(mx, sh, 16));
    float sm = 0.f;
#pragma unroll
    for (int ni = 0; ni < 8; ++ni) sm += __expf(v[ni] - mx);
#pragma unroll
    for (int sh = 1; sh < 16; sh <<= 1) sm += __shfl_xor(sm, sh, 16);
    const float lse = mx + __logf(sm);
    float cand = 0.f;
#pragma unroll
    for (int ni = 0; ni < 8; ++ni)
      if (ni == tj) cand = v[ni];                // positive-pair tile (uniform)
    const float vp = __shfl(cand, rloc, 16);
    lacc += vp - lse;                            // x16 lanes per row
  }
#pragma unroll
  for (int sh = 1; sh < 64; sh <<= 1) lacc += __shfl_xor(lacc, sh, 64);
  if (lane == 0) wred[w] = lacc;
  __syncthreads();
  if (t == 0) {
    float tot = 0.f;
#pragma unroll
    for (int i = 0; i < 8; ++i) tot += wred[i];
    // tot = 16 * sum_rows(pos) for this hw; loss = -sum/(HW*2B) with x16 dup
    atomicAdd(out, -tot * (1.0f / 2097152.0f));
  }
}

extern "C" void kernel_launch(void* const* d_in, const int* in_sizes, int n_in,
                              void* d_out, int out_size, void* d_ws, size_t ws_size,
                              hipStream_t stream) {
  const float* inp = (const float*)d_in[0];
  const float* tgt = (const float*)d_in[1];
  unsigned char* wsF = (unsigned char*)d_ws;
  k_transpose<<<dim3(8, 128, 2), 256, 0, stream>>>(inp, tgt, wsF, (float*)d_out);
  k_gram<<<dim3(HWPOS), 512, 0, stream>>>(wsF, (float*)d_out);
}

// Round 7
// 174.684 us; speedup vs baseline: 1.0287x; 1.0033x over previous
//
#include <hip/hip_runtime.h>
#include <stdint.h>

#define HWPOS 1024
#define CCH   256
#define RROWS 128   // 2B
#define EPSF  1.1920928955078125e-07f

typedef __attribute__((ext_vector_type(4))) float float4v;

// 64 partial-sum slots, padded to 64B each to spread atomic RMWs across
// L2 lines/channels (1024 same-address atomics was the suspected serial
// tail in k_gram). Zeroed by the first k_transpose launch (stream order
// + kernel-boundary acquire/release make this race-free).
__device__ float g_acc[64 * 16];

__device__ __forceinline__ uint32_t pk4_fp8(float a, float b, float c, float d) {
  int v = 0;
  v = __builtin_amdgcn_cvt_pk_fp8_f32(a, b, v, false);  // bytes 0,1
  v = __builtin_amdgcn_cvt_pk_fp8_f32(c, d, v, true);   // bytes 2,3
  return (uint32_t)v;
}

// ws layout (fp8 bytes), R-MAJOR: addr(r,hw,s) = r*262144 + hw*256 + s*16
//   s = swizzled 16B chunk slot: data chunk dd stored at s = dd ^ (r & 15)
//   -> per-256B-row image identical to prior versions; gram algebra unchanged.

// ---------------------------------------------------------------------------
// Kernel 1 (v13 = v11 structure, fp8): transpose [B,C,H,W] f32 -> ws fp8.
// Reverted to v11's register-load form (v12's global_load_lds staging was
// equal-speed; v11 is simpler). v13 change: grid split in two r-halves
// (diagnostic: pushes k_gram into the rocprof top-5) via r0 kernel arg;
// also zeroes g_acc in the first launch. Block = 128 hw x 128 c x 1 r.
// Reads: 2x512B segments per wave-load. Writes: 2KB spans (r-major ws).
// ---------------------------------------------------------------------------
__global__ __launch_bounds__(256, 4) void k_transpose(const float* __restrict__ inp,
                                                      const float* __restrict__ tgt,
                                                      unsigned char* __restrict__ wsF,
                                                      int r0) {
  __shared__ uint4 Ls[1024];        // [hwl 0..127][slot 0..7], 16 KB
  const int t    = threadIdx.x;
  const int hq   = t & 31;          // hw quad (4 hw) -> 128 hw per block
  const int ddl  = t >> 5;          // local c-chunk 0..7
  const int bx   = blockIdx.x;      // hw group (128 hw each), 0..7
  const int r    = r0 + blockIdx.y; // row 0..127
  const int half = blockIdx.z;      // c half 0..1
  if (r0 == 0 && bx == 0 && blockIdx.y == 0 && half == 0 && t < 64)
    g_acc[t * 16] = 0.0f;
  const int dd = half * 8 + ddl;    // global c-chunk 0..15
  const float* src = (r < 64) ? (inp + (size_t)r * CCH * HWPOS)
                              : (tgt + (size_t)(r - 64) * CCH * HWPOS);
  const float* p = src + (size_t)(dd * 16) * HWPOS + bx * 128 + hq * 4;
  float4 v[16];
#pragma unroll
  for (int e = 0; e < 16; ++e) v[e] = *(const float4*)(p + (size_t)e * HWPOS);
  // convert + stage to LDS (slot swizzled by hq&7 to spread banks)
  const int sbase = ddl ^ (hq & 7);
#pragma unroll
  for (int q = 0; q < 4; ++q) {
    float x[16];
#pragma unroll
    for (int e = 0; e < 16; ++e)
      x[e] = (q == 0) ? v[e].x : (q == 1) ? v[e].y : (q == 2) ? v[e].z : v[e].w;
    uint4 o;
    o.x = pk4_fp8(x[0],  x[1],  x[2],  x[3]);
    o.y = pk4_fp8(x[4],  x[5],  x[6],  x[7]);
    o.z = pk4_fp8(x[8],  x[9],  x[10], x[11]);
    o.w = pk4_fp8(x[12], x[13], x[14], x[15]);
    Ls[(hq * 4 + q) * 8 + sbase] = o;
  }
  __syncthreads();
  // write phase: 8 lanes (sl) emit one aligned 128B half-row per hw
  const int sl = t & 7;             // output slot within half-row
  const int hb = t >> 3;            // hw base 0..31
  const int mh = r & 7;
  const int half_out = half ^ ((r >> 3) & 1);
  const int ddn = sl ^ mh;          // local chunk that lands at slot sl
  const size_t gbase = (size_t)r * 262144 + (size_t)(bx * 128) * 256
                     + (size_t)(half_out * 128 + sl * 16);
#pragma unroll
  for (int j = 0; j < 4; ++j) {
    const int hwl = hb + 32 * j;
    uint4 d = Ls[hwl * 8 + (ddn ^ ((hwl >> 2) & 7))];
    *(uint4*)(wsF + gbase + (size_t)hwl * 256) = d;
  }
}

// ---------------------------------------------------------------------------
// Kernel 2 (v7, fp8): one block per hw; whole 32KB fp8 image in one LDS
// buffer; 8 waves x mfma_f32_16x16x32_fp8_fp8; fused masked log-softmax +
// positive-pair extraction. v7 change: partial sum goes to g_acc[hw&63]
// (64-way-spread atomics, 64B-padded slots) instead of 1024 serialized
// same-address atomicAdds on out[0]. All MFMA/softmax algebra unchanged.
// ---------------------------------------------------------------------------
__global__ __launch_bounds__(512, 4) void k_gram(const unsigned char* __restrict__ wsF) {
  __shared__ unsigned char Fs[32768];   // full fp8 image, swizzled
  __shared__ float sInv[RROWS];
  __shared__ float wred[8];
  const int t  = threadIdx.x;
  const int hw = blockIdx.x;
  const int lane = t & 63;
  const int w    = t >> 6;        // wave id 0..7 = row-tile
  const int lid  = lane & 15;
  const int quad = lane >> 4;
  float4v acc[8];
#pragma unroll
  for (int ni = 0; ni < 8; ++ni) acc[ni] = (float4v){0.f, 0.f, 0.f, 0.f};
#pragma unroll
  for (int it = 0; it < 4; ++it) {
    const int ch = it * 512 + t;                    // Fs chunk index 0..2047
    const size_t goff = (size_t)(ch >> 4) * 262144  // r page
                      + (size_t)hw * 256
                      + (size_t)(ch & 15) * 16;     // slot within row
    __builtin_amdgcn_global_load_lds(
        (const __attribute__((address_space(1))) unsigned int*)(wsF + goff),
        (__attribute__((address_space(3))) unsigned int*)(Fs + (size_t)ch * 16),
        16, 0, 0);
  }
  __syncthreads();
  const int rowA = (w << 4) | lid;
#pragma unroll
  for (int ks = 0; ks < 8; ++ks) {
    const int d    = 2 * ks + (quad >> 1);      // data chunk for this frag
    const int off  = ((d ^ lid) << 4) + (quad & 1) * 8;  // swizzled byte off
    long a = *(const long*)&Fs[rowA * 256 + off];
#pragma unroll
    for (int ni = 0; ni < 8; ++ni) {
      long b = *(const long*)&Fs[(((ni << 4) | lid)) * 256 + off];
      acc[ni] = __builtin_amdgcn_mfma_f32_16x16x32_fp8_fp8(a, b, acc[ni], 0, 0, 0);
    }
  }
  // diagonal extract (no dynamic indexing): tile w (uniform), elem lid&3
  {
    float diagv = 0.f;
#pragma unroll
    for (int ni = 0; ni < 8; ++ni) {
      if (ni == w) {
#pragma unroll
        for (int e = 0; e < 4; ++e)
          if (e == (lid & 3)) diagv = acc[ni][e];
      }
    }
    if ((lid >> 2) == quad) {
      sInv[(w << 4) | lid] = 1.0f / fmaxf(sqrtf(diagv), EPSF);
    }
  }
  __syncthreads();
  float invj[8];
#pragma unroll
  for (int ni = 0; ni < 8; ++ni) invj[ni] = sInv[(ni << 4) | lid];
  const int tj = (w + 4) & 7;     // partner col-tile (wave-uniform)
  float lacc = 0.f;
#pragma unroll
  for (int reg = 0; reg < 4; ++reg) {
    const int rloc = quad * 4 + reg;           // local row in tile
    const int rg   = (w << 4) | rloc;          // global row 0..127
    const float invi = sInv[rg];
    float v[8];
#pragma unroll
    for (int ni = 0; ni < 8; ++ni) v[ni] = 2.0f * acc[ni][reg] * invi * invj[ni];
#pragma unroll
    for (int ni = 0; ni < 8; ++ni)
      if (ni == w && lid == rloc) v[ni] = -3.0e38f;   // mask diagonal
    float mx = v[0];
#pragma unroll
    for (int ni = 1; ni < 8; ++ni) mx = fmaxf(mx, v[ni]);
#pragma unroll
    for (int sh = 1; sh < 16; sh <<= 1) mx = fmaxf(mx, __shfl_xor(mx, sh, 16));
    float sm = 0.f;
#pragma unroll
    for (int ni = 0; ni < 8; ++ni) sm += __expf(v[ni] - mx);
#pragma unroll
    for (int sh = 1; sh < 16; sh <<= 1) sm += __shfl_xor(sm, sh, 16);
    const float lse = mx + __logf(sm);
    float cand = 0.f;
#pragma unroll
    for (int ni = 0; ni < 8; ++ni)
      if (ni == tj) cand = v[ni];                // positive-pair tile (uniform)
    const float vp = __shfl(cand, rloc, 16);
    lacc += vp - lse;                            // x16 lanes per row
  }
#pragma unroll
  for (int sh = 1; sh < 64; sh <<= 1) lacc += __shfl_xor(lacc, sh, 64);
  if (lane == 0) wred[w] = lacc;
  __syncthreads();
  if (t == 0) {
    float tot = 0.f;
#pragma unroll
    for (int i = 0; i < 8; ++i) tot += wred[i];
    // tot = 16 * sum_rows(pos) for this hw; spread-atomic into 64 slots
    atomicAdd(&g_acc[(hw & 63) * 16], tot);
  }
}

// ---------------------------------------------------------------------------
// Kernel 3: final reduce of the 64 partial slots -> out[0].
// loss = -sum / (HW * 2B) with the x16 lane duplication (2097152 = 1024*128*16)
// ---------------------------------------------------------------------------
__global__ __launch_bounds__(64) void k_reduce(float* __restrict__ out) {
  const int t = threadIdx.x;
  float v = g_acc[t * 16];
#pragma unroll
  for (int sh = 1; sh < 64; sh <<= 1) v += __shfl_xor(v, sh, 64);
  if (t == 0) out[0] = -v * (1.0f / 2097152.0f);
}

extern "C" void kernel_launch(void* const* d_in, const int* in_sizes, int n_in,
                              void* d_out, int out_size, void* d_ws, size_t ws_size,
                              hipStream_t stream) {
  const float* inp = (const float*)d_in[0];
  const float* tgt = (const float*)d_in[1];
  unsigned char* wsF = (unsigned char*)d_ws;
  k_transpose<<<dim3(8, 64, 2), 256, 0, stream>>>(inp, tgt, wsF, 0);
  k_transpose<<<dim3(8, 64, 2), 256, 0, stream>>>(inp, tgt, wsF, 64);
  k_gram<<<dim3(HWPOS), 512, 0, stream>>>(wsF);
  k_reduce<<<1, 64, 0, stream>>>((float*)d_out);
}